// Round 4
// baseline (157.508 us; speedup 1.0000x reference)
//
#include <hip/hip_runtime.h>
#include <math.h>

#define N_     256
#define C_     2048
#define HW_    49
#define NW     16              // waves per block (1024 threads)
#define WCH    (C_/NW)         // 128 channels per wave
#define TILE_C 16              // channels per unrolled batch (loads in flight)
#define NTILE  (WCH/TILE_C)    // 8 batches per wave
#define NG     5               // groups: sum, u0, u1, t0, t1

// ---------------------------------------------------------------------------
// Fused kernel: one block per n (16 waves, 1 block/CU). Each wave streams its
// private 128-channel slice with DIRECT global loads (lane p owns position p;
// x[c*49+p] is a 196B-contiguous wave access). No x staging, no barriers in
// the stream loop. Weights are a per-channel float4 broadcast from LDS
// (~10 us/CU on the LDS pipe, under the 16.3 us HBM floor). Then block-level
// reduction of the 16x(5x49) partials + epilogue in-place.
// ---------------------------------------------------------------------------
__global__ __launch_bounds__(1024) void k_fused(const float* __restrict__ x,
                                                const float* __restrict__ mask,
                                                const float* __restrict__ Wm,
                                                const float* __restrict__ b,
                                                float* __restrict__ out) {
  const int n    = blockIdx.x;
  const int t    = threadIdx.x;
  const int wave = t >> 6;
  const int lane = t & 63;

  __shared__ float4 wt4[C_];           // 32,768 B: (W0u, W1u, W0t, W1t)
  __shared__ float  red[NW][NG*HW_];   // 15,680 B
  __shared__ float  rsum[NG*HW_];      //    980 B

  // weights: wt4[c] = (W[0,c], W[1,c], W[0,C+c], W[1,C+c])
  #pragma unroll
  for (int c = t; c < C_; c += 1024) {
    float4 w;
    w.x = Wm[c];            // W[0, c]      -> u0
    w.y = Wm[2*C_ + c];     // W[1, c]      -> u1
    w.z = Wm[C_   + c];     // W[0, C+c]    -> t0
    w.w = Wm[3*C_ + c];     // W[1, C+c]    -> t1
    wt4[c] = w;
  }
  __syncthreads();

  const float* wbase = x + ((size_t)n*C_ + (size_t)wave*WCH)*HW_;

  const int  p   = lane;
  const bool act = (lane < HW_);

  float a0 = 0.f, a1 = 0.f, a2 = 0.f, a3 = 0.f, a4 = 0.f;

  for (int tt = 0; tt < NTILE; ++tt) {
    const float* tb = wbase + (size_t)tt*TILE_C*HW_;

    // issue the whole batch of independent loads first (16 in flight/wave)
    float v[TILE_C];
    #pragma unroll
    for (int c = 0; c < TILE_C; ++c)
      v[c] = act ? tb[c*HW_ + p] : 0.f;

    #pragma unroll
    for (int c = 0; c < TILE_C; ++c) {
      const float4 w = wt4[wave*WCH + tt*TILE_C + c];  // broadcast ds_read_b128
      a0 += v[c];
      a1 = fmaf(v[c], w.x, a1);
      a2 = fmaf(v[c], w.y, a2);
      a3 = fmaf(v[c], w.z, a3);
      a4 = fmaf(v[c], w.w, a4);
    }
  }

  if (act) {
    red[wave][0*HW_ + p] = a0;
    red[wave][1*HW_ + p] = a1;
    red[wave][2*HW_ + p] = a2;
    red[wave][3*HW_ + p] = a3;
    red[wave][4*HW_ + p] = a4;
  }
  __syncthreads();

  // 16-way cross-wave reduction (threads 0..244)
  if (t < NG*HW_) {
    float s = 0.f;
    #pragma unroll
    for (int w = 0; w < NW; ++w) s += red[w][t];
    rsum[t] = s;
  }
  __syncthreads();

  // ---- epilogue: wave 0 only ----
  if (t < 64) {
    const int  pp  = t;
    const bool ac  = (pp < HW_);

    // threshold = mean(mask[n]); binary mask strict >
    float m = ac ? mask[n*HW_ + pp] : 0.f;
    float tot = m;
    #pragma unroll
    for (int off = 32; off; off >>= 1) tot += __shfl_xor(tot, off);
    const float thr = tot / 49.f;

    // masked_mean and first-index argmax over 49 positions
    float s  = ac ? rsum[0*HW_ + pp] : 0.f;
    float mm = ac ? ((m > thr) ? (s * (1.f/2048.f)) : 0.f) : -INFINITY;
    float best = mm;
    int   bidx = ac ? pp : 64;
    #pragma unroll
    for (int off = 32; off; off >>= 1) {
      float ov = __shfl_xor(best, off);
      int   oi = __shfl_xor(bidx, off);
      if (ov > best || (ov == best && oi < bidx)) { best = ov; bidx = oi; }
    }
    const int mi = bidx;   // uniform across wave

    const float u0mi = rsum[1*HW_ + mi];
    const float u1mi = rsum[2*HW_ + mi];

    float pred0 = 0.f, pred1 = 0.f;
    if (ac) {
      pred0 = fmaxf(u0mi + rsum[3*HW_ + pp] + b[0], 0.f);
      pred1 = fmaxf(u1mi + rsum[4*HW_ + pp] + b[1], 0.f);
      if (pp == mi) { pred0 = 0.f; pred1 = 0.f; }
    }

    // geometry
    const int ii = pp / 7,  jj = pp - ii*7;
    const int ai = mi / 7,  aj = mi - ai*7;
    const float ri = (float)(ii - ai) / 7.f;
    const float rj = (float)(jj - aj) / 7.f;
    const float dist = sqrtf(ri*ri + rj*rj);
    const float ang  = (atan2f(rj, ri) / 3.14159274101257324f + 1.f) * 0.5f;

    float gap = pred1 - ang;
    if (gap < 0.f) gap += 1.f;
    float gsum = ac ? gap : 0.f;
    #pragma unroll
    for (int off = 32; off; off >>= 1) gsum += __shfl_xor(gsum, off);
    const float gmean = gsum / 49.f;

    if (ac) {
      const float dl = pred0 - dist;
      const float ga = gap - gmean;
      out[n*HW_ + pp] = dl*dl + ga*ga;
    }
  }
}

extern "C" void kernel_launch(void* const* d_in, const int* in_sizes, int n_in,
                              void* d_out, int out_size, void* d_ws, size_t ws_size,
                              hipStream_t stream) {
  const float* x    = (const float*)d_in[0];  // (256, 2048, 7, 7)
  const float* mask = (const float*)d_in[1];  // (256, 7, 7)
  const float* Wm   = (const float*)d_in[2];  // (2, 4096)
  const float* b    = (const float*)d_in[3];  // (2,)
  float* out  = (float*)d_out;                // (256, 7, 7)
  (void)d_ws; (void)ws_size;                  // workspace not needed

  k_fused<<<dim3(N_), 1024, 0, stream>>>(x, mask, Wm, b, out);
}

// Round 5
// 157.085 us; speedup vs baseline: 1.0027x; 1.0027x over previous
//
#include <hip/hip_runtime.h>
#include <math.h>

#define N_     256
#define C_     2048
#define HW_    49
#define NW     16              // waves per block (1024 threads)
#define WCH    (C_/NW)         // 128 channels per wave
#define TILE_C 16              // channels per wave-tile
#define NTILE  (WCH/TILE_C)    // 8 tiles per wave
#define NG     5               // groups: sum, u0, u1, t0, t1
#define TFLOAT (TILE_C*HW_)    // 784 floats = 3136 B = 3*1024 + 64

// ---------------------------------------------------------------------------
// async 16B global->LDS copy (wave-uniform LDS base + lane*16, per-lane gaddr)
// ---------------------------------------------------------------------------
__device__ __forceinline__ void cp16(const void* gptr, unsigned lds_off) {
  __builtin_amdgcn_global_load_lds(
      (const __attribute__((address_space(1))) unsigned int*)gptr,
      (__attribute__((address_space(3))) unsigned int*)lds_off,
      16, 0, 0);
}

// stage one private 16ch x 49pos tile (3136 B): exactly 4 vmem ops per wave
// (3 full 1KiB segments + one 64B tail with lanes 0..3 active)
__device__ __forceinline__ void stage_tile(const float* src, unsigned lb,
                                           int lane) {
  const char* s = (const char*)src;
  #pragma unroll
  for (int i = 0; i < 3; ++i)
    cp16(s + i*1024 + lane*16, lb + (unsigned)(i*1024));
  if (lane < 4)
    cp16(s + 3072 + lane*16, lb + 3072u);
}

// ---------------------------------------------------------------------------
// Fused kernel (round-3 core + startup/tail overlap):
//  - tile 0 staging issued FIRST so HBM streaming starts at cycle ~0;
//    weight-phase latency hides under it (pre-loop __syncthreads drains
//    vmcnt to 0, so the loop's counted-vmcnt arithmetic is unchanged).
//  - epilogue operands (mask row, b) prefetched before the sync, removing
//    the cold ~900-cyc mask load from the serial tail.
//  - main stream identical to the best-measured round-3 kernel.
// ---------------------------------------------------------------------------
__global__ __launch_bounds__(1024) void k_fused(const float* __restrict__ x,
                                                const float* __restrict__ mask,
                                                const float* __restrict__ Wm,
                                                const float* __restrict__ b,
                                                float* __restrict__ out) {
  const int n    = blockIdx.x;
  const int t    = threadIdx.x;
  const int wave = t >> 6;
  const int lane = t & 63;

  __shared__ __align__(16) float buf[NW][2][TFLOAT];  // 100,352 B
  __shared__ float4 wt4[C_];                          //  32,768 B
  __shared__ float  red[NW][NG*HW_];                  //  15,680 B
  __shared__ float  rsum[NG*HW_];                     //     980 B

  const float* wbase = x + ((size_t)n*C_ + (size_t)wave*WCH)*HW_;
  const unsigned lb0 = (unsigned)(size_t)&buf[wave][0][0];
  const unsigned lb1 = (unsigned)(size_t)&buf[wave][1][0];

  stage_tile(wbase, lb0, lane);   // tile 0 in flight before anything else

  // epilogue operand prefetch (drained by the pre-loop barrier)
  float m_pref = 0.f;
  if (t < HW_) m_pref = mask[n*HW_ + t];    // wave 0 lanes 0..48
  const float b0 = b[0], b1 = b[1];         // uniform -> scalar loads

  // weights: wt4[c] = (W[0,c], W[1,c], W[0,C+c], W[1,C+c])
  #pragma unroll
  for (int c = t; c < C_; c += 1024) {
    float4 w;
    w.x = Wm[c];            // W[0, c]      -> u0
    w.y = Wm[2*C_ + c];     // W[1, c]      -> u1
    w.z = Wm[C_   + c];     // W[0, C+c]    -> t0
    w.w = Wm[3*C_ + c];     // W[1, C+c]    -> t1
    wt4[c] = w;
  }
  __syncthreads();   // wt4 + tile 0 visible; full drain -> clean vmcnt slate

  const int  p   = lane;
  const bool act = (lane < HW_);

  float a0 = 0.f, a1 = 0.f, a2 = 0.f, a3 = 0.f, a4 = 0.f;

  #pragma unroll 2
  for (int tt = 0; tt < NTILE; ++tt) {
    if (tt < NTILE-1) {
      stage_tile(wbase + (size_t)(tt+1)*TFLOAT,
                 (tt & 1) ? lb0 : lb1, lane);
      asm volatile("s_waitcnt vmcnt(4)" ::: "memory");  // tile tt landed,
    } else {                                            // tile tt+1 in flight
      asm volatile("s_waitcnt vmcnt(0)" ::: "memory");
    }

    if (act) {
      const float*  tl = &buf[wave][tt & 1][0];
      const float4* wp = &wt4[wave*WCH + tt*TILE_C];
      #pragma unroll
      for (int c = 0; c < TILE_C; ++c) {
        const float  v = tl[c*HW_ + p];   // <=2-way bank alias (free, m136)
        const float4 w = wp[c];           // same addr all lanes: broadcast
        a0 += v;
        a1 = fmaf(v, w.x, a1);
        a2 = fmaf(v, w.y, a2);
        a3 = fmaf(v, w.z, a3);
        a4 = fmaf(v, w.w, a4);
      }
    }
    // all ds_reads of this buffer complete before it can be overwritten
    asm volatile("s_waitcnt lgkmcnt(0)" ::: "memory");
  }

  if (act) {
    red[wave][0*HW_ + p] = a0;
    red[wave][1*HW_ + p] = a1;
    red[wave][2*HW_ + p] = a2;
    red[wave][3*HW_ + p] = a3;
    red[wave][4*HW_ + p] = a4;
  }
  __syncthreads();

  // 16-way cross-wave reduction (threads 0..244)
  if (t < NG*HW_) {
    float s = 0.f;
    #pragma unroll
    for (int w = 0; w < NW; ++w) s += red[w][t];
    rsum[t] = s;
  }
  __syncthreads();

  // ---- epilogue: wave 0 only ----
  if (t < 64) {
    const int  pp  = t;
    const bool ac  = (pp < HW_);

    // threshold = mean(mask[n]); binary mask strict >
    float m = ac ? m_pref : 0.f;
    float tot = m;
    #pragma unroll
    for (int off = 32; off; off >>= 1) tot += __shfl_xor(tot, off);
    const float thr = tot / 49.f;

    // masked_mean and first-index argmax over 49 positions
    float s  = ac ? rsum[0*HW_ + pp] : 0.f;
    float mm = ac ? ((m > thr) ? (s * (1.f/2048.f)) : 0.f) : -INFINITY;
    float best = mm;
    int   bidx = ac ? pp : 64;
    #pragma unroll
    for (int off = 32; off; off >>= 1) {
      float ov = __shfl_xor(best, off);
      int   oi = __shfl_xor(bidx, off);
      if (ov > best || (ov == best && oi < bidx)) { best = ov; bidx = oi; }
    }
    const int mi = bidx;   // uniform across wave

    const float u0mi = rsum[1*HW_ + mi];
    const float u1mi = rsum[2*HW_ + mi];

    float pred0 = 0.f, pred1 = 0.f;
    if (ac) {
      pred0 = fmaxf(u0mi + rsum[3*HW_ + pp] + b0, 0.f);
      pred1 = fmaxf(u1mi + rsum[4*HW_ + pp] + b1, 0.f);
      if (pp == mi) { pred0 = 0.f; pred1 = 0.f; }
    }

    // geometry
    const int ii = pp / 7,  jj = pp - ii*7;
    const int ai = mi / 7,  aj = mi - ai*7;
    const float ri = (float)(ii - ai) / 7.f;
    const float rj = (float)(jj - aj) / 7.f;
    const float dist = sqrtf(ri*ri + rj*rj);
    const float ang  = (atan2f(rj, ri) / 3.14159274101257324f + 1.f) * 0.5f;

    float gap = pred1 - ang;
    if (gap < 0.f) gap += 1.f;
    float gsum = ac ? gap : 0.f;
    #pragma unroll
    for (int off = 32; off; off >>= 1) gsum += __shfl_xor(gsum, off);
    const float gmean = gsum / 49.f;

    if (ac) {
      const float dl = pred0 - dist;
      const float ga = gap - gmean;
      out[n*HW_ + pp] = dl*dl + ga*ga;
    }
  }
}

extern "C" void kernel_launch(void* const* d_in, const int* in_sizes, int n_in,
                              void* d_out, int out_size, void* d_ws, size_t ws_size,
                              hipStream_t stream) {
  const float* x    = (const float*)d_in[0];  // (256, 2048, 7, 7)
  const float* mask = (const float*)d_in[1];  // (256, 7, 7)
  const float* Wm   = (const float*)d_in[2];  // (2, 4096)
  const float* b    = (const float*)d_in[3];  // (2,)
  float* out  = (float*)d_out;                // (256, 7, 7)
  (void)d_ws; (void)ws_size;                  // workspace not needed

  k_fused<<<dim3(N_), 1024, 0, stream>>>(x, mask, Wm, b, out);
}